// Round 2
// baseline (552.676 us; speedup 1.0000x reference)
//
#include <hip/hip_runtime.h>
#include <hip/hip_bf16.h>
#include <stdint.h>

#define B_ 2
#define S_ 2048
#define D_ 2048
#define H_ 32
#define KVH_ 8
#define HD_ 64

typedef __bf16 bf16x8 __attribute__((ext_vector_type(8)));
typedef float f32x4 __attribute__((ext_vector_type(4)));

#define MFMA16(a, b, c) __builtin_amdgcn_mfma_f32_16x16x32_bf16((a), (b), (c), 0, 0, 0)

typedef __attribute__((address_space(1))) void gvoid_t;
typedef __attribute__((address_space(3))) void lvoid_t;

__device__ __forceinline__ void async_ld16(__hip_bfloat16* lds, const __hip_bfloat16* g) {
  __builtin_amdgcn_global_load_lds((gvoid_t*)(void*)(g), (lvoid_t*)(lds), 16, 0, 0);
}

__device__ __forceinline__ unsigned short f2bu(float f) {
  __hip_bfloat16 h = __float2bfloat16(f);
  return *reinterpret_cast<unsigned short*>(&h);
}

// ---------------- fp32 -> bf16 cast (n % 4 == 0) ----------------
__global__ void cast_bf16_kernel(const float* __restrict__ in,
                                 unsigned short* __restrict__ out, int n4) {
  int i = blockIdx.x * blockDim.x + threadIdx.x;
  if (i >= n4) return;
  float4 v = reinterpret_cast<const float4*>(in)[i];
  ushort4 o;
  o.x = f2bu(v.x); o.y = f2bu(v.y); o.z = f2bu(v.z); o.w = f2bu(v.w);
  reinterpret_cast<ushort4*>(out)[i] = o;
}

// ---------------- C = A[M,K] @ W[N,K]^T, bf16 in, fp32 acc ----------------
// MODE 0: bf16 C row-major [M,N] -> Cb
// MODE 1: fp32 C row-major [M,N] -> Cf
// MODE 2: K epilogue: fp32 [B,KVH,S,HD] -> Cf, bf16 same layout -> Cb
// MODE 3: V epilogue: fp32 [B,KVH,S,HD] -> Cf, bf16 transposed [B,KVH,HD,S] -> Cb
template <int MODE>
__global__ __launch_bounds__(256, 2)
void gemm_bt(const __hip_bfloat16* __restrict__ A,
             const __hip_bfloat16* __restrict__ W,
             float* __restrict__ Cf, __hip_bfloat16* __restrict__ Cb,
             int M, int N, int K) {
  __shared__ __align__(16) __hip_bfloat16 sA[128 * 32];
  __shared__ __align__(16) __hip_bfloat16 sB[128 * 32];
  const int tid = threadIdx.x;
  const int lane = tid & 63;
  const int wv = tid >> 6;
  const int l15 = lane & 15, l4 = lane >> 4;
  const int bm = blockIdx.x * 128, bn = blockIdx.y * 128;
  const int wm = (wv >> 1) * 64, wn = (wv & 1) * 64;

  const int ci0 = tid, ci1 = tid + 256;
  const __hip_bfloat16* gA0 = A + (size_t)(bm + (ci0 >> 2)) * K + (ci0 & 3) * 8;
  const __hip_bfloat16* gA1 = A + (size_t)(bm + (ci1 >> 2)) * K + (ci1 & 3) * 8;
  const __hip_bfloat16* gB0 = W + (size_t)(bn + (ci0 >> 2)) * K + (ci0 & 3) * 8;
  const __hip_bfloat16* gB1 = W + (size_t)(bn + (ci1 >> 2)) * K + (ci1 & 3) * 8;
  __hip_bfloat16* lA0 = &sA[ci0 * 8];
  __hip_bfloat16* lA1 = &sA[ci1 * 8];
  __hip_bfloat16* lB0 = &sB[ci0 * 8];
  __hip_bfloat16* lB1 = &sB[ci1 * 8];

  f32x4 acc[4][4];
#pragma unroll
  for (int i = 0; i < 4; ++i) {
#pragma unroll
    for (int j = 0; j < 4; ++j) acc[i][j] = f32x4{0.f, 0.f, 0.f, 0.f};
  }

  for (int k0 = 0; k0 < K; k0 += 32) {
    async_ld16(lA0, gA0 + k0);
    async_ld16(lA1, gA1 + k0);
    async_ld16(lB0, gB0 + k0);
    async_ld16(lB1, gB1 + k0);
    __syncthreads();
    bf16x8 af[4], bfr[4];
#pragma unroll
    for (int i = 0; i < 4; ++i)
      af[i] = *reinterpret_cast<const bf16x8*>(&sA[(wm + i * 16 + l15) * 32 + l4 * 8]);
#pragma unroll
    for (int j = 0; j < 4; ++j)
      bfr[j] = *reinterpret_cast<const bf16x8*>(&sB[(wn + j * 16 + l15) * 32 + l4 * 8]);
#pragma unroll
    for (int i = 0; i < 4; ++i) {
#pragma unroll
      for (int j = 0; j < 4; ++j) acc[i][j] = MFMA16(af[i], bfr[j], acc[i][j]);
    }
    __syncthreads();
  }

#pragma unroll
  for (int i = 0; i < 4; ++i) {
#pragma unroll
    for (int j = 0; j < 4; ++j) {
      const int col = bn + wn + j * 16 + l15;
#pragma unroll
      for (int r = 0; r < 4; ++r) {
        const int row = bm + wm + i * 16 + l4 * 4 + r;
        const float v = acc[i][j][r];
        if (MODE == 0) {
          Cb[(size_t)row * N + col] = __float2bfloat16(v);
        } else if (MODE == 1) {
          Cf[(size_t)row * N + col] = v;
        } else {
          const int b = row >> 11, s = row & 2047;
          const int g = col >> 6, hd = col & 63;
          const size_t idx = ((size_t)(b * KVH_ + g) * S_ + s) * HD_ + hd;
          Cf[idx] = v;
          if (MODE == 2)
            Cb[idx] = __float2bfloat16(v);
          else
            Cb[((size_t)(b * KVH_ + g) * HD_ + hd) * S_ + s] = __float2bfloat16(v);
        }
      }
    }
  }
}

// ---------------- fused causal GQA flash attention ----------------
// Qb: [B*S, H*HD] bf16; Kb: [B,KVH,S,HD] bf16; Vtb: [B,KVH,HD,S] bf16
// AOb: [B*S, H*HD] bf16 (softmax(QK^T/8 + causal) @ V)
__global__ __launch_bounds__(256, 2)
void attn_fused(const __hip_bfloat16* __restrict__ Qb,
                const __hip_bfloat16* __restrict__ Kb,
                const __hip_bfloat16* __restrict__ Vtb,
                __hip_bfloat16* __restrict__ AOb) {
  constexpr int SKS = 72;   // sK row stride (elems), 144 B = 9*16
  constexpr int SVS = 136;  // sV row stride, 272 B = 17*16
  constexpr int SPS = 72;   // sP row stride
  __shared__ __align__(16) __hip_bfloat16 sK[128 * SKS];
  __shared__ __align__(16) __hip_bfloat16 sV[64 * SVS];
  __shared__ __align__(16) __hip_bfloat16 sP[4 * 32 * SPS];

  const int tid = threadIdx.x;
  const int lane = tid & 63;
  const int wv = tid >> 6;
  const int l15 = lane & 15, l4 = lane >> 4;
  const int qi = blockIdx.x;  // q tile (128 rows)
  const int h = blockIdx.y;
  const int b = blockIdx.z;
  const int g = h >> 2;  // GQA group

  // Q fragments (A-operand layout), loaded straight from global
  bf16x8 qf[2][2];
  {
    const __hip_bfloat16* Qp =
        Qb + ((size_t)(b * S_ + qi * 128 + wv * 32)) * D_ + h * HD_;
#pragma unroll
    for (int i = 0; i < 2; ++i) {
#pragma unroll
      for (int c = 0; c < 2; ++c)
        qf[i][c] = *reinterpret_cast<const bf16x8*>(
            Qp + (size_t)(i * 16 + l15) * D_ + c * 32 + l4 * 8);
    }
  }

  float mst[2][4], lst[2][4];
  f32x4 oacc[2][4];
#pragma unroll
  for (int i = 0; i < 2; ++i) {
#pragma unroll
    for (int r = 0; r < 4; ++r) { mst[i][r] = -3.0e38f; lst[i][r] = 0.0f; }
#pragma unroll
    for (int j = 0; j < 4; ++j) oacc[i][j] = f32x4{0.f, 0.f, 0.f, 0.f};
  }

  const __hip_bfloat16* Kp = Kb + (size_t)(b * KVH_ + g) * S_ * HD_;
  const __hip_bfloat16* Vp = Vtb + (size_t)(b * KVH_ + g) * HD_ * S_;
  __hip_bfloat16* sPw = sP + wv * 32 * SPS;
  const float CE = 0.125f * 1.4426950408889634f;  // scale * log2(e)

  for (int ki = 0; ki <= qi; ++ki) {
    // stage K tile [128 rows(kpos) x 64 cols(d)] -> sK : 1024 x bf16x8 chunks
#pragma unroll
    for (int t = 0; t < 4; ++t) {
      const int ci = tid + t * 256;
      const int r = ci >> 3, c = ci & 7;
      *reinterpret_cast<bf16x8*>(&sK[r * SKS + c * 8]) =
          *reinterpret_cast<const bf16x8*>(Kp + (size_t)(ki * 128 + r) * HD_ + c * 8);
    }
    // stage V^T tile [64 rows(hd) x 128 cols(kpos)] -> sV : 1024 x bf16x8 chunks
#pragma unroll
    for (int t = 0; t < 4; ++t) {
      const int ci = tid + t * 256;
      const int r = ci >> 4, c = ci & 15;
      *reinterpret_cast<bf16x8*>(&sV[r * SVS + c * 8]) =
          *reinterpret_cast<const bf16x8*>(Vp + (size_t)r * S_ + ki * 128 + c * 8);
    }
    __syncthreads();

    // raw scores: [32 q x 128 k] per wave
    f32x4 sc[2][8];
#pragma unroll
    for (int jn = 0; jn < 8; ++jn) {
      const bf16x8 k0 = *reinterpret_cast<const bf16x8*>(&sK[(jn * 16 + l15) * SKS + l4 * 8]);
      const bf16x8 k1 = *reinterpret_cast<const bf16x8*>(&sK[(jn * 16 + l15) * SKS + 32 + l4 * 8]);
#pragma unroll
      for (int i = 0; i < 2; ++i) {
        f32x4 t = f32x4{0.f, 0.f, 0.f, 0.f};
        t = MFMA16(qf[i][0], k0, t);
        t = MFMA16(qf[i][1], k1, t);
        sc[i][jn] = t;
      }
    }

    // causal mask on diagonal tile
    if (ki == qi) {
#pragma unroll
      for (int i = 0; i < 2; ++i) {
#pragma unroll
        for (int jn = 0; jn < 8; ++jn) {
          const int kp = jn * 16 + l15;
#pragma unroll
          for (int r = 0; r < 4; ++r) {
            const int qp = wv * 32 + i * 16 + l4 * 4 + r;
            if (kp > qp) sc[i][jn][r] = -3.0e38f;
          }
        }
      }
    }

    // online softmax (exp2 domain), per row (i,r)
    float alph[2][4];
#pragma unroll
    for (int i = 0; i < 2; ++i) {
#pragma unroll
      for (int r = 0; r < 4; ++r) {
        float mx = sc[i][0][r];
#pragma unroll
        for (int jn = 1; jn < 8; ++jn) mx = fmaxf(mx, sc[i][jn][r]);
#pragma unroll
        for (int off = 1; off < 16; off <<= 1) mx = fmaxf(mx, __shfl_xor(mx, off, 64));
        const float Mn = fmaxf(mst[i][r], mx * CE);
        const float al = exp2f(mst[i][r] - Mn);
        float rs = 0.f;
#pragma unroll
        for (int jn = 0; jn < 8; ++jn) {
          const float pv = exp2f(fmaf(sc[i][jn][r], CE, -Mn));
          sc[i][jn][r] = pv;
          rs += pv;
        }
#pragma unroll
        for (int off = 1; off < 16; off <<= 1) rs += __shfl_xor(rs, off, 64);
        mst[i][r] = Mn;
        lst[i][r] = lst[i][r] * al + rs;
        alph[i][r] = al;
      }
    }
#pragma unroll
    for (int i = 0; i < 2; ++i) {
#pragma unroll
      for (int j = 0; j < 4; ++j) {
#pragma unroll
        for (int r = 0; r < 4; ++r) oacc[i][j][r] *= alph[i][r];
      }
    }

    // P @ V in two 64-wide halves; P: C-layout -> LDS -> A-layout (per-wave region)
#pragma unroll
    for (int hh = 0; hh < 2; ++hh) {
#pragma unroll
      for (int i = 0; i < 2; ++i) {
#pragma unroll
        for (int jj = 0; jj < 4; ++jj) {
#pragma unroll
          for (int r = 0; r < 4; ++r)
            sPw[(i * 16 + l4 * 4 + r) * SPS + jj * 16 + l15] =
                __float2bfloat16(sc[i][hh * 4 + jj][r]);
        }
      }
#pragma unroll
      for (int kc = 0; kc < 2; ++kc) {
        bf16x8 vf[4];
#pragma unroll
        for (int jn = 0; jn < 4; ++jn)
          vf[jn] = *reinterpret_cast<const bf16x8*>(
              &sV[(jn * 16 + l15) * SVS + hh * 64 + kc * 32 + l4 * 8]);
#pragma unroll
        for (int i = 0; i < 2; ++i) {
          const bf16x8 pf = *reinterpret_cast<const bf16x8*>(
              &sPw[(i * 16 + l15) * SPS + kc * 32 + l4 * 8]);
#pragma unroll
          for (int jn = 0; jn < 4; ++jn) oacc[i][jn] = MFMA16(pf, vf[jn], oacc[i][jn]);
        }
      }
    }
    __syncthreads();
  }

  // normalize + store bf16
#pragma unroll
  for (int i = 0; i < 2; ++i) {
    float inv[4];
#pragma unroll
    for (int r = 0; r < 4; ++r) inv[r] = 1.0f / lst[i][r];
#pragma unroll
    for (int jn = 0; jn < 4; ++jn) {
#pragma unroll
      for (int r = 0; r < 4; ++r) {
        const int qp = qi * 128 + wv * 32 + i * 16 + l4 * 4 + r;
        AOb[(size_t)(b * S_ + qp) * D_ + h * HD_ + jn * 16 + l15] =
            __float2bfloat16(oacc[i][jn][r] * inv[r]);
      }
    }
  }
}

extern "C" void kernel_launch(void* const* d_in, const int* in_sizes, int n_in,
                              void* d_out, int out_size, void* d_ws, size_t ws_size,
                              hipStream_t stream) {
  (void)in_sizes; (void)n_in; (void)out_size; (void)ws_size;
  const float* x = (const float*)d_in[0];
  // d_in[1] = attention_mask (causal, hardcoded in attn kernel)
  const float* Wq = (const float*)d_in[2];
  const float* Wk = (const float*)d_in[3];
  const float* Wv = (const float*)d_in[4];
  const float* Wo = (const float*)d_in[5];

  float* outO = (float*)d_out;                              // [B,S,D]
  float* outK = outO + (size_t)B_ * S_ * D_;                // [B,KVH,S,HD]
  float* outV = outK + (size_t)B_ * KVH_ * S_ * HD_;        // [B,KVH,S,HD]

  char* p = (char*)d_ws;
  __hip_bfloat16* xb  = (__hip_bfloat16*)p; p += (size_t)B_ * S_ * D_ * 2;
  __hip_bfloat16* Wqb = (__hip_bfloat16*)p; p += (size_t)D_ * D_ * 2;
  __hip_bfloat16* Wkb = (__hip_bfloat16*)p; p += (size_t)KVH_ * HD_ * D_ * 2;
  __hip_bfloat16* Wvb = (__hip_bfloat16*)p; p += (size_t)KVH_ * HD_ * D_ * 2;
  __hip_bfloat16* Wob = (__hip_bfloat16*)p; p += (size_t)D_ * D_ * 2;
  __hip_bfloat16* Qbf = (__hip_bfloat16*)p; p += (size_t)B_ * S_ * D_ * 2;
  __hip_bfloat16* Kbf = (__hip_bfloat16*)p; p += (size_t)B_ * KVH_ * S_ * HD_ * 2;
  __hip_bfloat16* Vtb = (__hip_bfloat16*)p; p += (size_t)B_ * KVH_ * S_ * HD_ * 2;
  __hip_bfloat16* AOb = (__hip_bfloat16*)p; p += (size_t)B_ * S_ * D_ * 2;

  auto cast = [&](const float* src, __hip_bfloat16* dst, size_t n) {
    const int n4 = (int)(n / 4);
    cast_bf16_kernel<<<dim3((n4 + 255) / 256), dim3(256), 0, stream>>>(
        src, (unsigned short*)dst, n4);
  };
  cast(x, xb, (size_t)B_ * S_ * D_);
  cast(Wq, Wqb, (size_t)D_ * D_);
  cast(Wk, Wkb, (size_t)KVH_ * HD_ * D_);
  cast(Wv, Wvb, (size_t)KVH_ * HD_ * D_);
  cast(Wo, Wob, (size_t)D_ * D_);

  // Q = x @ Wq^T  -> bf16 [4096, 2048]
  gemm_bt<0><<<dim3(32, 16), dim3(256), 0, stream>>>(xb, Wqb, (float*)nullptr, Qbf, 4096, 2048, 2048);
  // K = x @ Wk^T  -> fp32 d_out [B,KVH,S,HD] + bf16 same layout
  gemm_bt<2><<<dim3(32, 4), dim3(256), 0, stream>>>(xb, Wkb, outK, Kbf, 4096, 512, 2048);
  // V = x @ Wv^T  -> fp32 d_out [B,KVH,S,HD] + bf16 transposed [B,KVH,HD,S]
  gemm_bt<3><<<dim3(32, 4), dim3(256), 0, stream>>>(xb, Wvb, outV, Vtb, 4096, 512, 2048);
  // fused causal attention
  attn_fused<<<dim3(16, 32, 2), dim3(256), 0, stream>>>(Qbf, Kbf, Vtb, AOb);
  // output = AO @ Wo^T -> fp32 d_out [B,S,D]
  gemm_bt<1><<<dim3(32, 16), dim3(256), 0, stream>>>(AOb, Wob, outO, (__hip_bfloat16*)nullptr, 4096, 2048, 2048);
}

// Round 3
// 435.007 us; speedup vs baseline: 1.2705x; 1.2705x over previous
//
#include <hip/hip_runtime.h>
#include <hip/hip_bf16.h>
#include <stdint.h>

#define B_ 2
#define S_ 2048
#define D_ 2048
#define H_ 32
#define KVH_ 8
#define HD_ 64

typedef __bf16 bf16x8 __attribute__((ext_vector_type(8)));
typedef float f32x4 __attribute__((ext_vector_type(4)));

#define MFMA16(a, b, c) __builtin_amdgcn_mfma_f32_16x16x32_bf16((a), (b), (c), 0, 0, 0)

typedef __attribute__((address_space(1))) void gvoid_t;
typedef __attribute__((address_space(3))) void lvoid_t;

__device__ __forceinline__ void async_ld16(__hip_bfloat16* lds, const __hip_bfloat16* g) {
  __builtin_amdgcn_global_load_lds((gvoid_t*)(void*)(g), (lvoid_t*)(lds), 16, 0, 0);
}

__device__ __forceinline__ unsigned short f2bu(float f) {
  __hip_bfloat16 h = __float2bfloat16(f);
  return *reinterpret_cast<unsigned short*>(&h);
}

// ---------------- fp32 -> bf16 cast (n % 4 == 0) ----------------
__global__ void cast_bf16_kernel(const float* __restrict__ in,
                                 unsigned short* __restrict__ out, int n4) {
  int i = blockIdx.x * blockDim.x + threadIdx.x;
  if (i >= n4) return;
  float4 v = reinterpret_cast<const float4*>(in)[i];
  ushort4 o;
  o.x = f2bu(v.x); o.y = f2bu(v.y); o.z = f2bu(v.z); o.w = f2bu(v.w);
  reinterpret_cast<ushort4*>(out)[i] = o;
}

// ---------------- C = A[M,K] @ W[N,K]^T, bf16 in, fp32 acc ----------------
template <int MODE>
__global__ __launch_bounds__(256, 2)
void gemm_bt(const __hip_bfloat16* __restrict__ A,
             const __hip_bfloat16* __restrict__ W,
             float* __restrict__ Cf, __hip_bfloat16* __restrict__ Cb,
             int M, int N, int K) {
  __shared__ __align__(16) __hip_bfloat16 sA[128 * 32];
  __shared__ __align__(16) __hip_bfloat16 sB[128 * 32];
  const int tid = threadIdx.x;
  const int lane = tid & 63;
  const int wv = tid >> 6;
  const int l15 = lane & 15, l4 = lane >> 4;
  const int bm = blockIdx.x * 128, bn = blockIdx.y * 128;
  const int wm = (wv >> 1) * 64, wn = (wv & 1) * 64;

  const int ci0 = tid, ci1 = tid + 256;
  const __hip_bfloat16* gA0 = A + (size_t)(bm + (ci0 >> 2)) * K + (ci0 & 3) * 8;
  const __hip_bfloat16* gA1 = A + (size_t)(bm + (ci1 >> 2)) * K + (ci1 & 3) * 8;
  const __hip_bfloat16* gB0 = W + (size_t)(bn + (ci0 >> 2)) * K + (ci0 & 3) * 8;
  const __hip_bfloat16* gB1 = W + (size_t)(bn + (ci1 >> 2)) * K + (ci1 & 3) * 8;
  __hip_bfloat16* lA0 = &sA[ci0 * 8];
  __hip_bfloat16* lA1 = &sA[ci1 * 8];
  __hip_bfloat16* lB0 = &sB[ci0 * 8];
  __hip_bfloat16* lB1 = &sB[ci1 * 8];

  f32x4 acc[4][4];
#pragma unroll
  for (int i = 0; i < 4; ++i) {
#pragma unroll
    for (int j = 0; j < 4; ++j) acc[i][j] = f32x4{0.f, 0.f, 0.f, 0.f};
  }

  for (int k0 = 0; k0 < K; k0 += 32) {
    async_ld16(lA0, gA0 + k0);
    async_ld16(lA1, gA1 + k0);
    async_ld16(lB0, gB0 + k0);
    async_ld16(lB1, gB1 + k0);
    __syncthreads();
    bf16x8 af[4], bfr[4];
#pragma unroll
    for (int i = 0; i < 4; ++i)
      af[i] = *reinterpret_cast<const bf16x8*>(&sA[(wm + i * 16 + l15) * 32 + l4 * 8]);
#pragma unroll
    for (int j = 0; j < 4; ++j)
      bfr[j] = *reinterpret_cast<const bf16x8*>(&sB[(wn + j * 16 + l15) * 32 + l4 * 8]);
#pragma unroll
    for (int i = 0; i < 4; ++i) {
#pragma unroll
      for (int j = 0; j < 4; ++j) acc[i][j] = MFMA16(af[i], bfr[j], acc[i][j]);
    }
    __syncthreads();
  }

#pragma unroll
  for (int i = 0; i < 4; ++i) {
#pragma unroll
    for (int j = 0; j < 4; ++j) {
      const int col = bn + wn + j * 16 + l15;
#pragma unroll
      for (int r = 0; r < 4; ++r) {
        const int row = bm + wm + i * 16 + l4 * 4 + r;
        const float v = acc[i][j][r];
        if (MODE == 0) {
          Cb[(size_t)row * N + col] = __float2bfloat16(v);
        } else if (MODE == 1) {
          Cf[(size_t)row * N + col] = v;
        } else {
          const int b = row >> 11, s = row & 2047;
          const int g = col >> 6, hd = col & 63;
          const size_t idx = ((size_t)(b * KVH_ + g) * S_ + s) * HD_ + hd;
          Cf[idx] = v;
          if (MODE == 2)
            Cb[idx] = __float2bfloat16(v);
          else
            Cb[((size_t)(b * KVH_ + g) * HD_ + hd) * S_ + s] = __float2bfloat16(v);
        }
      }
    }
  }
}

// ---------------- fused causal GQA flash attention, paired q-tiles ----------------
// Block bx handles q-tiles qa=bx (0..7) and qb=15-bx (8..15): (qa+1)+(qb+1)=17
// tile-steps per block -> perfectly balanced grid of 8x32x2=512 blocks (2/CU).
// Qb: [B*S, H*HD] bf16; Kb: [B,KVH,S,HD] bf16; Vtb: [B,KVH,HD,S] bf16
__global__ __launch_bounds__(256, 2)
void attn_fused(const __hip_bfloat16* __restrict__ Qb,
                const __hip_bfloat16* __restrict__ Kb,
                const __hip_bfloat16* __restrict__ Vtb,
                __hip_bfloat16* __restrict__ AOb) {
  constexpr int SKS = 72;   // sK row stride (elems)
  constexpr int SVS = 136;  // sV row stride
  constexpr int SPS = 72;   // sP row stride
  __shared__ __align__(16) __hip_bfloat16 sK[128 * SKS];
  __shared__ __align__(16) __hip_bfloat16 sV[64 * SVS];
  __shared__ __align__(16) __hip_bfloat16 sP[4 * 32 * SPS];

  const int tid = threadIdx.x;
  const int lane = tid & 63;
  const int wv = tid >> 6;
  const int l15 = lane & 15, l4 = lane >> 4;
  const int qa = blockIdx.x;       // 0..7
  const int qb = 15 - qa;          // 8..15
  const int h = blockIdx.y;
  const int b = blockIdx.z;
  const int g = h >> 2;            // GQA group

  // Q fragments (A-operand layout) for both tiles
  bf16x8 qfA[2][2], qfB[2][2];
  {
    const __hip_bfloat16* QpA =
        Qb + ((size_t)(b * S_ + qa * 128 + wv * 32)) * D_ + h * HD_;
    const __hip_bfloat16* QpB =
        Qb + ((size_t)(b * S_ + qb * 128 + wv * 32)) * D_ + h * HD_;
#pragma unroll
    for (int i = 0; i < 2; ++i) {
#pragma unroll
      for (int c = 0; c < 2; ++c) {
        qfA[i][c] = *reinterpret_cast<const bf16x8*>(
            QpA + (size_t)(i * 16 + l15) * D_ + c * 32 + l4 * 8);
        qfB[i][c] = *reinterpret_cast<const bf16x8*>(
            QpB + (size_t)(i * 16 + l15) * D_ + c * 32 + l4 * 8);
      }
    }
  }

  float mstA[2][4], mstB[2][4];
  f32x4 oaccA[2][4], oaccB[2][4];
  f32x4 laccA[2], laccB[2];
#pragma unroll
  for (int i = 0; i < 2; ++i) {
#pragma unroll
    for (int r = 0; r < 4; ++r) { mstA[i][r] = -3.0e38f; mstB[i][r] = -3.0e38f; }
    laccA[i] = f32x4{0.f, 0.f, 0.f, 0.f};
    laccB[i] = f32x4{0.f, 0.f, 0.f, 0.f};
#pragma unroll
    for (int j = 0; j < 4; ++j) {
      oaccA[i][j] = f32x4{0.f, 0.f, 0.f, 0.f};
      oaccB[i][j] = f32x4{0.f, 0.f, 0.f, 0.f};
    }
  }

  bf16x8 vone;
#pragma unroll
  for (int j = 0; j < 8; ++j) vone[j] = (__bf16)1.0f;

  const __hip_bfloat16* Kp = Kb + (size_t)(b * KVH_ + g) * S_ * HD_;
  const __hip_bfloat16* Vp = Vtb + (size_t)(b * KVH_ + g) * HD_ * S_;
  __hip_bfloat16* sPw = sP + wv * 32 * SPS;
  const float CE = 0.125f * 1.4426950408889634f;  // scale * log2(e)

  // process one q-tile against the staged K/V tile
  auto process = [&](bf16x8 (&qf)[2][2], float (&mst)[2][4], f32x4 (&lacc)[2],
                     f32x4 (&oacc)[2][4], bool diag) {
    f32x4 sc[2][8];
#pragma unroll
    for (int jn = 0; jn < 8; ++jn) {
      const bf16x8 k0 = *reinterpret_cast<const bf16x8*>(&sK[(jn * 16 + l15) * SKS + l4 * 8]);
      const bf16x8 k1 = *reinterpret_cast<const bf16x8*>(&sK[(jn * 16 + l15) * SKS + 32 + l4 * 8]);
#pragma unroll
      for (int i = 0; i < 2; ++i) {
        f32x4 t = f32x4{0.f, 0.f, 0.f, 0.f};
        t = MFMA16(qf[i][0], k0, t);
        t = MFMA16(qf[i][1], k1, t);
        sc[i][jn] = t;
      }
    }

    if (diag) {
#pragma unroll
      for (int i = 0; i < 2; ++i) {
#pragma unroll
        for (int jn = 0; jn < 8; ++jn) {
          const int kp = jn * 16 + l15;
#pragma unroll
          for (int r = 0; r < 4; ++r) {
            const int qp = wv * 32 + i * 16 + l4 * 4 + r;
            if (kp > qp) sc[i][jn][r] = -3.0e38f;
          }
        }
      }
    }

    // online softmax: only the row-max needs cross-lane reduction
    float alph[2][4];
#pragma unroll
    for (int i = 0; i < 2; ++i) {
#pragma unroll
      for (int r = 0; r < 4; ++r) {
        float mx = sc[i][0][r];
#pragma unroll
        for (int jn = 1; jn < 8; ++jn) mx = fmaxf(mx, sc[i][jn][r]);
#pragma unroll
        for (int off = 1; off < 16; off <<= 1) mx = fmaxf(mx, __shfl_xor(mx, off, 64));
        const float Mn = fmaxf(mst[i][r], mx * CE);
        alph[i][r] = exp2f(mst[i][r] - Mn);
        mst[i][r] = Mn;
#pragma unroll
        for (int jn = 0; jn < 8; ++jn)
          sc[i][jn][r] = exp2f(fmaf(sc[i][jn][r], CE, -Mn));
      }
    }
#pragma unroll
    for (int i = 0; i < 2; ++i) {
#pragma unroll
      for (int r = 0; r < 4; ++r) lacc[i][r] *= alph[i][r];
#pragma unroll
      for (int j = 0; j < 4; ++j) {
#pragma unroll
        for (int r = 0; r < 4; ++r) oacc[i][j][r] *= alph[i][r];
      }
    }

    // P @ V in two 64-wide halves; P: C-layout -> LDS -> A-layout (per-wave region)
    // row-sum l accumulated by an extra MFMA against all-ones B (no shuffles)
#pragma unroll
    for (int hh = 0; hh < 2; ++hh) {
#pragma unroll
      for (int i = 0; i < 2; ++i) {
#pragma unroll
        for (int jj = 0; jj < 4; ++jj) {
#pragma unroll
          for (int r = 0; r < 4; ++r)
            sPw[(i * 16 + l4 * 4 + r) * SPS + jj * 16 + l15] =
                __float2bfloat16(sc[i][hh * 4 + jj][r]);
        }
      }
#pragma unroll
      for (int kc = 0; kc < 2; ++kc) {
        bf16x8 vf[4];
#pragma unroll
        for (int jn = 0; jn < 4; ++jn)
          vf[jn] = *reinterpret_cast<const bf16x8*>(
              &sV[(jn * 16 + l15) * SVS + hh * 64 + kc * 32 + l4 * 8]);
#pragma unroll
        for (int i = 0; i < 2; ++i) {
          const bf16x8 pf = *reinterpret_cast<const bf16x8*>(
              &sPw[(i * 16 + l15) * SPS + kc * 32 + l4 * 8]);
#pragma unroll
          for (int jn = 0; jn < 4; ++jn) oacc[i][jn] = MFMA16(pf, vf[jn], oacc[i][jn]);
          lacc[i] = MFMA16(pf, vone, lacc[i]);
        }
      }
    }
  };

  for (int ki = 0; ki <= qb; ++ki) {
    // stage K tile [128 x 64] and V^T tile [64 x 128] (1024 bf16x8 chunks each)
#pragma unroll
    for (int t = 0; t < 4; ++t) {
      const int ci = tid + t * 256;
      const int r = ci >> 3, c = ci & 7;
      *reinterpret_cast<bf16x8*>(&sK[r * SKS + c * 8]) =
          *reinterpret_cast<const bf16x8*>(Kp + (size_t)(ki * 128 + r) * HD_ + c * 8);
    }
#pragma unroll
    for (int t = 0; t < 4; ++t) {
      const int ci = tid + t * 256;
      const int r = ci >> 4, c = ci & 15;
      *reinterpret_cast<bf16x8*>(&sV[r * SVS + c * 8]) =
          *reinterpret_cast<const bf16x8*>(Vp + (size_t)r * S_ + ki * 128 + c * 8);
    }
    __syncthreads();

    process(qfB, mstB, laccB, oaccB, ki == qb);
    if (ki <= qa) process(qfA, mstA, laccA, oaccA, ki == qa);
    __syncthreads();
  }

  // normalize + store bf16 (each lane holds its own row's l in lacc C-layout)
#pragma unroll
  for (int tsel = 0; tsel < 2; ++tsel) {
    const int qt = tsel ? qb : qa;
    f32x4 (&oacc)[2][4] = tsel ? oaccB : oaccA;
    f32x4 (&lacc)[2] = tsel ? laccB : laccA;
#pragma unroll
    for (int i = 0; i < 2; ++i) {
      float inv[4];
#pragma unroll
      for (int r = 0; r < 4; ++r) inv[r] = 1.0f / lacc[i][r];
#pragma unroll
      for (int jn = 0; jn < 4; ++jn) {
#pragma unroll
        for (int r = 0; r < 4; ++r) {
          const int qp = qt * 128 + wv * 32 + i * 16 + l4 * 4 + r;
          AOb[(size_t)(b * S_ + qp) * D_ + h * HD_ + jn * 16 + l15] =
              __float2bfloat16(oacc[i][jn][r] * inv[r]);
        }
      }
    }
  }
}

extern "C" void kernel_launch(void* const* d_in, const int* in_sizes, int n_in,
                              void* d_out, int out_size, void* d_ws, size_t ws_size,
                              hipStream_t stream) {
  (void)in_sizes; (void)n_in; (void)out_size; (void)ws_size;
  const float* x = (const float*)d_in[0];
  const float* Wq = (const float*)d_in[2];
  const float* Wk = (const float*)d_in[3];
  const float* Wv = (const float*)d_in[4];
  const float* Wo = (const float*)d_in[5];

  float* outO = (float*)d_out;                              // [B,S,D]
  float* outK = outO + (size_t)B_ * S_ * D_;                // [B,KVH,S,HD]
  float* outV = outK + (size_t)B_ * KVH_ * S_ * HD_;        // [B,KVH,S,HD]

  char* p = (char*)d_ws;
  __hip_bfloat16* xb  = (__hip_bfloat16*)p; p += (size_t)B_ * S_ * D_ * 2;
  __hip_bfloat16* Wqb = (__hip_bfloat16*)p; p += (size_t)D_ * D_ * 2;
  __hip_bfloat16* Wkb = (__hip_bfloat16*)p; p += (size_t)KVH_ * HD_ * D_ * 2;
  __hip_bfloat16* Wvb = (__hip_bfloat16*)p; p += (size_t)KVH_ * HD_ * D_ * 2;
  __hip_bfloat16* Wob = (__hip_bfloat16*)p; p += (size_t)D_ * D_ * 2;
  __hip_bfloat16* Qbf = (__hip_bfloat16*)p; p += (size_t)B_ * S_ * D_ * 2;
  __hip_bfloat16* Kbf = (__hip_bfloat16*)p; p += (size_t)B_ * KVH_ * S_ * HD_ * 2;
  __hip_bfloat16* Vtb = (__hip_bfloat16*)p; p += (size_t)B_ * KVH_ * S_ * HD_ * 2;
  __hip_bfloat16* AOb = (__hip_bfloat16*)p; p += (size_t)B_ * S_ * D_ * 2;

  auto cast = [&](const float* src, __hip_bfloat16* dst, size_t n) {
    const int n4 = (int)(n / 4);
    cast_bf16_kernel<<<dim3((n4 + 255) / 256), dim3(256), 0, stream>>>(
        src, (unsigned short*)dst, n4);
  };
  cast(x, xb, (size_t)B_ * S_ * D_);
  cast(Wq, Wqb, (size_t)D_ * D_);
  cast(Wk, Wkb, (size_t)KVH_ * HD_ * D_);
  cast(Wv, Wvb, (size_t)KVH_ * HD_ * D_);
  cast(Wo, Wob, (size_t)D_ * D_);

  // Q = x @ Wq^T  -> bf16 [4096, 2048]
  gemm_bt<0><<<dim3(32, 16), dim3(256), 0, stream>>>(xb, Wqb, (float*)nullptr, Qbf, 4096, 2048, 2048);
  // K = x @ Wk^T  -> fp32 d_out [B,KVH,S,HD] + bf16 same layout
  gemm_bt<2><<<dim3(32, 4), dim3(256), 0, stream>>>(xb, Wkb, outK, Kbf, 4096, 512, 2048);
  // V = x @ Wv^T  -> fp32 d_out [B,KVH,S,HD] + bf16 transposed [B,KVH,HD,S]
  gemm_bt<3><<<dim3(32, 4), dim3(256), 0, stream>>>(xb, Wvb, outV, Vtb, 4096, 512, 2048);
  // fused causal attention (paired, balanced q-tiles)
  attn_fused<<<dim3(8, 32, 2), dim3(256), 0, stream>>>(Qbf, Kbf, Vtb, AOb);
  // output = AO @ Wo^T -> fp32 d_out [B,S,D]
  gemm_bt<1><<<dim3(32, 16), dim3(256), 0, stream>>>(AOb, Wob, outO, (__hip_bfloat16*)nullptr, 4096, 2048, 2048);
}

// Round 4
// 373.641 us; speedup vs baseline: 1.4792x; 1.1642x over previous
//
#include <hip/hip_runtime.h>
#include <hip/hip_bf16.h>
#include <stdint.h>

#define B_ 2
#define S_ 2048
#define D_ 2048
#define H_ 32
#define KVH_ 8
#define HD_ 64

typedef __bf16 bf16x8 __attribute__((ext_vector_type(8)));
typedef float f32x4 __attribute__((ext_vector_type(4)));

#define MFMA16(a, b, c) __builtin_amdgcn_mfma_f32_16x16x32_bf16((a), (b), (c), 0, 0, 0)

typedef __attribute__((address_space(1))) void gvoid_t;
typedef __attribute__((address_space(3))) void lvoid_t;

__device__ __forceinline__ void async_ld16(__hip_bfloat16* lds, const __hip_bfloat16* g) {
  __builtin_amdgcn_global_load_lds((gvoid_t*)(void*)(g), (lvoid_t*)(lds), 16, 0, 0);
}

__device__ __forceinline__ unsigned short f2bu(float f) {
  __hip_bfloat16 h = __float2bfloat16(f);
  return *reinterpret_cast<unsigned short*>(&h);
}

// ---------------- fp32 -> bf16 cast (n % 4 == 0) ----------------
__global__ void cast_bf16_kernel(const float* __restrict__ in,
                                 unsigned short* __restrict__ out, int n4) {
  int i = blockIdx.x * blockDim.x + threadIdx.x;
  if (i >= n4) return;
  float4 v = reinterpret_cast<const float4*>(in)[i];
  ushort4 o;
  o.x = f2bu(v.x); o.y = f2bu(v.y); o.z = f2bu(v.z); o.w = f2bu(v.w);
  reinterpret_cast<ushort4*>(out)[i] = o;
}

// ---------------- C = A[M,K] @ W[N,K]^T, bf16 in, fp32 acc ----------------
// MODE 1: fp32 C row-major [M,N] -> Cf          (O-projection)
// MODE 4: fused QKV epilogue over N=3072:
//   cols    0..2047 -> Cb  = Qbf bf16 row-major [M,2048]
//   cols 2048..2559 -> Cf  = outK fp32 [B,KVH,S,HD], Cb2 = Kbf bf16 same
//   cols 2560..3071 -> Cf2 = outV fp32 [B,KVH,S,HD], Cb3 = Vtb bf16 [B,KVH,HD,S]
template <int MODE>
__global__ __launch_bounds__(256, 2)
void gemm_bt(const __hip_bfloat16* __restrict__ A,
             const __hip_bfloat16* __restrict__ W,
             float* __restrict__ Cf, __hip_bfloat16* __restrict__ Cb,
             float* __restrict__ Cf2, __hip_bfloat16* __restrict__ Cb2,
             __hip_bfloat16* __restrict__ Cb3,
             int M, int N, int K) {
  __shared__ __align__(16) __hip_bfloat16 sA[128 * 32];
  __shared__ __align__(16) __hip_bfloat16 sB[128 * 32];
  const int tid = threadIdx.x;
  const int lane = tid & 63;
  const int wv = tid >> 6;
  const int l15 = lane & 15, l4 = lane >> 4;
  const int bm = blockIdx.x * 128, bn = blockIdx.y * 128;
  const int wm = (wv >> 1) * 64, wn = (wv & 1) * 64;

  const int ci0 = tid, ci1 = tid + 256;
  const __hip_bfloat16* gA0 = A + (size_t)(bm + (ci0 >> 2)) * K + (ci0 & 3) * 8;
  const __hip_bfloat16* gA1 = A + (size_t)(bm + (ci1 >> 2)) * K + (ci1 & 3) * 8;
  const __hip_bfloat16* gB0 = W + (size_t)(bn + (ci0 >> 2)) * K + (ci0 & 3) * 8;
  const __hip_bfloat16* gB1 = W + (size_t)(bn + (ci1 >> 2)) * K + (ci1 & 3) * 8;
  __hip_bfloat16* lA0 = &sA[ci0 * 8];
  __hip_bfloat16* lA1 = &sA[ci1 * 8];
  __hip_bfloat16* lB0 = &sB[ci0 * 8];
  __hip_bfloat16* lB1 = &sB[ci1 * 8];

  f32x4 acc[4][4];
#pragma unroll
  for (int i = 0; i < 4; ++i) {
#pragma unroll
    for (int j = 0; j < 4; ++j) acc[i][j] = f32x4{0.f, 0.f, 0.f, 0.f};
  }

  for (int k0 = 0; k0 < K; k0 += 32) {
    async_ld16(lA0, gA0 + k0);
    async_ld16(lA1, gA1 + k0);
    async_ld16(lB0, gB0 + k0);
    async_ld16(lB1, gB1 + k0);
    __syncthreads();
    bf16x8 af[4], bfr[4];
#pragma unroll
    for (int i = 0; i < 4; ++i)
      af[i] = *reinterpret_cast<const bf16x8*>(&sA[(wm + i * 16 + l15) * 32 + l4 * 8]);
#pragma unroll
    for (int j = 0; j < 4; ++j)
      bfr[j] = *reinterpret_cast<const bf16x8*>(&sB[(wn + j * 16 + l15) * 32 + l4 * 8]);
#pragma unroll
    for (int i = 0; i < 4; ++i) {
#pragma unroll
      for (int j = 0; j < 4; ++j) acc[i][j] = MFMA16(af[i], bfr[j], acc[i][j]);
    }
    __syncthreads();
  }

#pragma unroll
  for (int i = 0; i < 4; ++i) {
#pragma unroll
    for (int j = 0; j < 4; ++j) {
      const int col = bn + wn + j * 16 + l15;
#pragma unroll
      for (int r = 0; r < 4; ++r) {
        const int row = bm + wm + i * 16 + l4 * 4 + r;
        const float v = acc[i][j][r];
        if (MODE == 1) {
          Cf[(size_t)row * N + col] = v;
        } else {  // MODE 4
          if (bn < 2048) {
            Cb[(size_t)row * 2048 + col] = __float2bfloat16(v);
          } else {
            const int bb = row >> 11, s = row & 2047;
            const int kv = col - 2048;
            if (kv < 512) {
              const int g = kv >> 6, hd = kv & 63;
              const size_t idx = ((size_t)(bb * KVH_ + g) * S_ + s) * HD_ + hd;
              Cf[idx] = v;
              Cb2[idx] = __float2bfloat16(v);
            } else {
              const int vv = kv - 512;
              const int g = vv >> 6, hd = vv & 63;
              const size_t idx = ((size_t)(bb * KVH_ + g) * S_ + s) * HD_ + hd;
              Cf2[idx] = v;
              Cb3[((size_t)(bb * KVH_ + g) * HD_ + hd) * S_ + s] = __float2bfloat16(v);
            }
          }
        }
      }
    }
  }
}

// ---------------- fused causal GQA flash attention, paired q-tiles ----------------
// Block bx handles q-tiles qa=bx (0..7) and qb=15-bx (8..15): 17 tile-steps.
// Grid 8x32x2 = 512 blocks (2/CU, balanced). Reg-prefetch K/V staging;
// XOR-swizzled sP (conflict-free P pack).
__global__ __launch_bounds__(256, 2)
void attn_fused(const __hip_bfloat16* __restrict__ Qb,
                const __hip_bfloat16* __restrict__ Kb,
                const __hip_bfloat16* __restrict__ Vtb,
                __hip_bfloat16* __restrict__ AOb) {
  constexpr int SKS = 72;   // sK row stride (elems)
  constexpr int SVS = 136;  // sV row stride
  constexpr int SPS = 64;   // sP row stride (XOR-swizzled blocks, no pad)
  __shared__ __align__(16) __hip_bfloat16 sK[128 * SKS];
  __shared__ __align__(16) __hip_bfloat16 sV[64 * SVS];
  __shared__ __align__(16) __hip_bfloat16 sP[4 * 32 * SPS];

  const int tid = threadIdx.x;
  const int lane = tid & 63;
  const int wv = tid >> 6;
  const int l15 = lane & 15, l4 = lane >> 4;
  const int qa = blockIdx.x;       // 0..7
  const int qb = 15 - qa;          // 8..15
  const int h = blockIdx.y;
  const int b = blockIdx.z;
  const int g = h >> 2;            // GQA group

  bf16x8 qfA[2][2], qfB[2][2];
  {
    const __hip_bfloat16* QpA =
        Qb + ((size_t)(b * S_ + qa * 128 + wv * 32)) * D_ + h * HD_;
    const __hip_bfloat16* QpB =
        Qb + ((size_t)(b * S_ + qb * 128 + wv * 32)) * D_ + h * HD_;
#pragma unroll
    for (int i = 0; i < 2; ++i) {
#pragma unroll
      for (int c = 0; c < 2; ++c) {
        qfA[i][c] = *reinterpret_cast<const bf16x8*>(
            QpA + (size_t)(i * 16 + l15) * D_ + c * 32 + l4 * 8);
        qfB[i][c] = *reinterpret_cast<const bf16x8*>(
            QpB + (size_t)(i * 16 + l15) * D_ + c * 32 + l4 * 8);
      }
    }
  }

  float mstA[2][4], mstB[2][4];
  f32x4 oaccA[2][4], oaccB[2][4];
  f32x4 laccA[2], laccB[2];
#pragma unroll
  for (int i = 0; i < 2; ++i) {
#pragma unroll
    for (int r = 0; r < 4; ++r) { mstA[i][r] = -3.0e38f; mstB[i][r] = -3.0e38f; }
    laccA[i] = f32x4{0.f, 0.f, 0.f, 0.f};
    laccB[i] = f32x4{0.f, 0.f, 0.f, 0.f};
#pragma unroll
    for (int j = 0; j < 4; ++j) {
      oaccA[i][j] = f32x4{0.f, 0.f, 0.f, 0.f};
      oaccB[i][j] = f32x4{0.f, 0.f, 0.f, 0.f};
    }
  }

  bf16x8 vone;
#pragma unroll
  for (int j = 0; j < 8; ++j) vone[j] = (__bf16)1.0f;

  const __hip_bfloat16* Kp = Kb + (size_t)(b * KVH_ + g) * S_ * HD_;
  const __hip_bfloat16* Vp = Vtb + (size_t)(b * KVH_ + g) * HD_ * S_;
  __hip_bfloat16* sPw = sP + wv * 32 * SPS;
  const float CE = 0.125f * 1.4426950408889634f;  // scale * log2(e)

  auto process = [&](bf16x8 (&qf)[2][2], float (&mst)[2][4], f32x4 (&lacc)[2],
                     f32x4 (&oacc)[2][4], bool diag) {
    f32x4 sc[2][8];
#pragma unroll
    for (int jn = 0; jn < 8; ++jn) {
      const bf16x8 k0 = *reinterpret_cast<const bf16x8*>(&sK[(jn * 16 + l15) * SKS + l4 * 8]);
      const bf16x8 k1 = *reinterpret_cast<const bf16x8*>(&sK[(jn * 16 + l15) * SKS + 32 + l4 * 8]);
#pragma unroll
      for (int i = 0; i < 2; ++i) {
        f32x4 t = f32x4{0.f, 0.f, 0.f, 0.f};
        t = MFMA16(qf[i][0], k0, t);
        t = MFMA16(qf[i][1], k1, t);
        sc[i][jn] = t;
      }
    }

    if (diag) {
#pragma unroll
      for (int i = 0; i < 2; ++i) {
#pragma unroll
        for (int jn = 0; jn < 8; ++jn) {
          const int kp = jn * 16 + l15;
#pragma unroll
          for (int r = 0; r < 4; ++r) {
            const int qp = wv * 32 + i * 16 + l4 * 4 + r;
            if (kp > qp) sc[i][jn][r] = -3.0e38f;
          }
        }
      }
    }

    float alph[2][4];
#pragma unroll
    for (int i = 0; i < 2; ++i) {
#pragma unroll
      for (int r = 0; r < 4; ++r) {
        float mx = sc[i][0][r];
#pragma unroll
        for (int jn = 1; jn < 8; ++jn) mx = fmaxf(mx, sc[i][jn][r]);
#pragma unroll
        for (int off = 1; off < 16; off <<= 1) mx = fmaxf(mx, __shfl_xor(mx, off, 64));
        const float Mn = fmaxf(mst[i][r], mx * CE);
        alph[i][r] = exp2f(mst[i][r] - Mn);
        mst[i][r] = Mn;
#pragma unroll
        for (int jn = 0; jn < 8; ++jn)
          sc[i][jn][r] = exp2f(fmaf(sc[i][jn][r], CE, -Mn));
      }
    }
#pragma unroll
    for (int i = 0; i < 2; ++i) {
#pragma unroll
      for (int r = 0; r < 4; ++r) lacc[i][r] *= alph[i][r];
#pragma unroll
      for (int j = 0; j < 4; ++j) {
#pragma unroll
        for (int r = 0; r < 4; ++r) oacc[i][j][r] *= alph[i][r];
      }
    }

    // P @ V; P packed via XOR-swizzled per-wave LDS (conflict-free writes).
    // phys col-block = jj ^ ((row>>2)&3); row-sum via MFMA against ones.
#pragma unroll
    for (int hh = 0; hh < 2; ++hh) {
#pragma unroll
      for (int i = 0; i < 2; ++i) {
#pragma unroll
        for (int jj = 0; jj < 4; ++jj) {
#pragma unroll
          for (int r = 0; r < 4; ++r)
            sPw[(i * 16 + l4 * 4 + r) * SPS + ((jj ^ l4) * 16 + l15)] =
                __float2bfloat16(sc[i][hh * 4 + jj][r]);
        }
      }
      const int gr = (l15 >> 2) & 3;
#pragma unroll
      for (int kc = 0; kc < 2; ++kc) {
        bf16x8 vf[4];
#pragma unroll
        for (int jn = 0; jn < 4; ++jn)
          vf[jn] = *reinterpret_cast<const bf16x8*>(
              &sV[(jn * 16 + l15) * SVS + hh * 64 + kc * 32 + l4 * 8]);
#pragma unroll
        for (int i = 0; i < 2; ++i) {
          const bf16x8 pf = *reinterpret_cast<const bf16x8*>(
              &sPw[(i * 16 + l15) * SPS + (((kc * 2 + (l4 >> 1)) ^ gr) * 16 + (l4 & 1) * 8)]);
#pragma unroll
          for (int jn = 0; jn < 4; ++jn) oacc[i][jn] = MFMA16(pf, vf[jn], oacc[i][jn]);
          lacc[i] = MFMA16(pf, vone, lacc[i]);
        }
      }
    }
  };

  // K/V tile register prefetch (4+4 bf16x8 chunks per thread)
  bf16x8 kreg[4], vreg[4];
  auto load_tile = [&](int ki) {
#pragma unroll
    for (int t = 0; t < 4; ++t) {
      const int ci = tid + t * 256;
      kreg[t] = *reinterpret_cast<const bf16x8*>(
          Kp + (size_t)(ki * 128 + (ci >> 3)) * HD_ + (ci & 7) * 8);
    }
#pragma unroll
    for (int t = 0; t < 4; ++t) {
      const int ci = tid + t * 256;
      vreg[t] = *reinterpret_cast<const bf16x8*>(
          Vp + (size_t)(ci >> 4) * S_ + ki * 128 + (ci & 15) * 8);
    }
  };

  load_tile(0);
  for (int ki = 0; ki <= qb; ++ki) {
    // commit prefetched tile to LDS (prev iter's trailing barrier protects reads)
#pragma unroll
    for (int t = 0; t < 4; ++t) {
      const int ci = tid + t * 256;
      *reinterpret_cast<bf16x8*>(&sK[(ci >> 3) * SKS + (ci & 7) * 8]) = kreg[t];
    }
#pragma unroll
    for (int t = 0; t < 4; ++t) {
      const int ci = tid + t * 256;
      *reinterpret_cast<bf16x8*>(&sV[(ci >> 4) * SVS + (ci & 15) * 8]) = vreg[t];
    }
    __syncthreads();
    if (ki < qb) load_tile(ki + 1);  // overlap global latency with compute

    process(qfB, mstB, laccB, oaccB, ki == qb);
    if (ki <= qa) process(qfA, mstA, laccA, oaccA, ki == qa);
    __syncthreads();
  }

  // normalize + store bf16 (per-lane l in C-layout)
#pragma unroll
  for (int tsel = 0; tsel < 2; ++tsel) {
    const int qt = tsel ? qb : qa;
    f32x4 (&oacc)[2][4] = tsel ? oaccB : oaccA;
    f32x4 (&lacc)[2] = tsel ? laccB : laccA;
#pragma unroll
    for (int i = 0; i < 2; ++i) {
      float inv[4];
#pragma unroll
      for (int r = 0; r < 4; ++r) inv[r] = 1.0f / lacc[i][r];
#pragma unroll
      for (int jn = 0; jn < 4; ++jn) {
#pragma unroll
        for (int r = 0; r < 4; ++r) {
          const int qp = qt * 128 + wv * 32 + i * 16 + l4 * 4 + r;
          AOb[(size_t)(b * S_ + qp) * D_ + h * HD_ + jn * 16 + l15] =
              __float2bfloat16(oacc[i][jn][r] * inv[r]);
        }
      }
    }
  }
}

extern "C" void kernel_launch(void* const* d_in, const int* in_sizes, int n_in,
                              void* d_out, int out_size, void* d_ws, size_t ws_size,
                              hipStream_t stream) {
  (void)in_sizes; (void)n_in; (void)out_size; (void)ws_size;
  const float* x = (const float*)d_in[0];
  const float* Wq = (const float*)d_in[2];
  const float* Wk = (const float*)d_in[3];
  const float* Wv = (const float*)d_in[4];
  const float* Wo = (const float*)d_in[5];

  float* outO = (float*)d_out;                              // [B,S,D]
  float* outK = outO + (size_t)B_ * S_ * D_;                // [B,KVH,S,HD]
  float* outV = outK + (size_t)B_ * KVH_ * S_ * HD_;        // [B,KVH,S,HD]

  char* p = (char*)d_ws;
  __hip_bfloat16* xb    = (__hip_bfloat16*)p; p += (size_t)B_ * S_ * D_ * 2;
  __hip_bfloat16* Wqkvb = (__hip_bfloat16*)p; p += (size_t)3072 * D_ * 2;
  __hip_bfloat16* Wob   = (__hip_bfloat16*)p; p += (size_t)D_ * D_ * 2;
  __hip_bfloat16* Qbf   = (__hip_bfloat16*)p; p += (size_t)B_ * S_ * D_ * 2;
  __hip_bfloat16* Kbf   = (__hip_bfloat16*)p; p += (size_t)B_ * KVH_ * S_ * HD_ * 2;
  __hip_bfloat16* Vtb   = (__hip_bfloat16*)p; p += (size_t)B_ * KVH_ * S_ * HD_ * 2;
  __hip_bfloat16* AOb   = (__hip_bfloat16*)p; p += (size_t)B_ * S_ * D_ * 2;

  auto cast = [&](const float* src, __hip_bfloat16* dst, size_t n) {
    const int n4 = (int)(n / 4);
    cast_bf16_kernel<<<dim3((n4 + 255) / 256), dim3(256), 0, stream>>>(
        src, (unsigned short*)dst, n4);
  };
  cast(x, xb, (size_t)B_ * S_ * D_);
  // combined [Wq; Wk; Wv] -> [3072, 2048] bf16
  cast(Wq, Wqkvb, (size_t)D_ * D_);
  cast(Wk, Wqkvb + (size_t)2048 * D_, (size_t)KVH_ * HD_ * D_);
  cast(Wv, Wqkvb + (size_t)2560 * D_, (size_t)KVH_ * HD_ * D_);
  cast(Wo, Wob, (size_t)D_ * D_);

  // fused QKV: [4096,2048] @ [3072,2048]^T
  gemm_bt<4><<<dim3(32, 24), dim3(256), 0, stream>>>(
      xb, Wqkvb, outK, Qbf, outV, Kbf, Vtb, 4096, 3072, 2048);
  // fused causal attention (paired, balanced q-tiles)
  attn_fused<<<dim3(8, 32, 2), dim3(256), 0, stream>>>(Qbf, Kbf, Vtb, AOb);
  // output = AO @ Wo^T -> fp32 d_out [B,S,D]
  gemm_bt<1><<<dim3(32, 16), dim3(256), 0, stream>>>(
      AOb, Wob, outO, nullptr, nullptr, nullptr, nullptr, 4096, 2048, 2048);
}